// Round 12
// baseline (321.256 us; speedup 1.0000x reference)
//
#include <hip/hip_runtime.h>

// LSTM RNN: B=2048, L=256 (257 scan steps), F=64, H=32, K=2.
// R13: BARRIER-FREE, 2 batches per wave, 1 wave/SIMD.
//  256 wgs x 256 thr (4 waves); wave w owns batches wgb+2w, wgb+2w+1 END-TO-END.
//  Gate compute: [2 x 64] @ [64 x 256] via 16 N-tiles x K-chain(2) = 32 MFMA
//  (M rows = 2 batches x dup8; C rows give batch = row&1 = reg index).
//  Lane l owns feature l of both batches: its gate value for gate gt sits in
//  tile gt*4+q, col n2, regs {0,1} (q*16+n2 == l) -> 3-cndmask tile select.
//  h-exchange INTRA-WAVE via per-wave LDS (same-wave DS in-order): no
//  __syncthreads in the 257-step loop. Logit diff every step by every wave
//  (own 2 batches), raw-stashed; softplus in 3-stage epilogue (R10's).
//  Rationale: R7 (this family @2 waves/SIMD, 1 batch/wave) ran 1378cy/step ->
//  per-SIMD MFMA ~8cy; at 1 wave/SIMD, 34 MFMA = 272cy matrix + ~350cy issue,
//  no barrier/rendezvous (R10's ~600cy/step stall component).
//  Gate cols pre-scaled by -L2E (i,f,o) / -2*L2E (g); cs = -2*L2E*c.

typedef __attribute__((ext_vector_type(8))) short bf16x8;
typedef __attribute__((ext_vector_type(4))) float f32x4;

#define L2E 1.44269504088896340736f
#define LN2 0.69314718055994530942f

__device__ __forceinline__ short f2bf(float x) {
    unsigned u = __builtin_bit_cast(unsigned, x);
    unsigned r = (u + 0x7FFFu + ((u >> 16) & 1u)) >> 16;
    return (short)r;
}

__global__ __launch_bounds__(256) void lstm_kernel(
    const int* __restrict__ s, const float* __restrict__ g,
    const float* __restrict__ W_emb, const float* __restrict__ b_emb,
    const float* __restrict__ W_g1, const float* __restrict__ b_g1,
    const float* __restrict__ W_g2, const float* __restrict__ b_g2,
    const float* __restrict__ W_gh, const float* __restrict__ b_gh,
    const float* __restrict__ W_gc, const float* __restrict__ b_gc,
    const float* __restrict__ Wi, const float* __restrict__ Wh,
    const float* __restrict__ b_lstm, const float* __restrict__ W_amp,
    const float* __restrict__ b_amp, float* __restrict__ out)
{
    __shared__ float Bx[35 * 256];              // 0-31: W_g2@Wi; 32-33: W_emb@Wi; 34: const (pre-scaled)
    __shared__ unsigned char sp_l[260];         // packed tokens: bit b of sp_l[t] = s_pad[b][t], 8 batches
    __shared__ __align__(16) short Hl[4][2][128]; // per-wave h dbuf: [batch(2)*64 + f]
    __shared__ __align__(16) float dLb[256 * 8];// raw logit diffs (bias folded): [t(256)][b(8)]
    __shared__ float red2[8][32];               // epilogue partials

    const int tid = threadIdx.x;
    const int w   = tid >> 6;     // wave 0..3; owns batches 2w, 2w+1
    const int l   = tid & 63;     // lane; owns feature f = l of both batches
    const int n2  = l & 15;       // MFMA col
    const int q   = l >> 4;       // MFMA k-quad
    const int wgb = blockIdx.x * 8;
    const int bat0 = wgb + 2 * w;

    // ---------- Setup: folded B rows into LDS, pre-scaled by activation constants ----------
    {
        const int n = tid;
        // cols [0,64)=i, [64,128)=f: -L2E; [128,192)=g: -2*L2E; [192,256)=o: -L2E
        const float sc = (n >= 128 && n < 192) ? (-2.0f * L2E) : (-L2E);
        float acc[35];
        #pragma unroll
        for (int i = 0; i < 35; ++i) acc[i] = 0.f;
        for (int f = 0; f < 64; ++f) {
            float wi = Wi[f * 256 + n] * sc;
            #pragma unroll
            for (int k = 0; k < 32; ++k) acc[k] += W_g2[k * 64 + f] * wi;  // uniform
            acc[32] += W_emb[f] * wi;
            acc[33] += W_emb[64 + f] * wi;
            acc[34] += (b_emb[f] + b_g2[f]) * wi;
        }
        acc[34] += b_lstm[n] * sc;
        #pragma unroll
        for (int i = 0; i < 35; ++i) Bx[i * 256 + n] = acc[i];
        // token staging: sp_l[t+1] bits = s[:, t] for 8 batch rows
        unsigned v = 0;
        #pragma unroll
        for (int b = 0; b < 8; ++b)
            v |= (unsigned)(s[(wgb + b) * 256 + n] & 1) << b;
        sp_l[n + 1] = (unsigned char)v;
        if (n == 0) sp_l[0] = 0;
        if (n < 3) sp_l[257 + n] = 0;
    }
    __syncthreads();

    // ---------- static fragments: full Wh (16 col-tiles x K-chain 2), pre-scaled ----------
    bf16x8 Bf[16][2];   // 128 VGPRs
    #pragma unroll
    for (int m = 0; m < 16; ++m) {
        const int n = m * 16 + n2;
        const float scg = (m >= 8 && m < 12) ? (-2.0f * L2E) : (-L2E);
        #pragma unroll
        for (int kf = 0; kf < 2; ++kf)
            #pragma unroll
            for (int j = 0; j < 8; ++j)
                Bf[m][kf][j] = f2bf(Wh[(kf * 32 + q * 8 + j) * 256 + n] * scg);
    }

    // per-lane gate base consts at col n = gt*64 + l, for both batches
    float y0b[4][2], Dsel[4];
    {
        #pragma unroll
        for (int b = 0; b < 2; ++b) {
            const float gb = g[bat0 + b];
            float atv[32];
            #pragma unroll
            for (int k = 0; k < 32; ++k)
                atv[k] = tanhf(gb * W_g1[k] + b_g1[k]);
            #pragma unroll
            for (int gt = 0; gt < 4; ++gt) {
                const int n = gt * 64 + l;
                float a = Bx[32 * 256 + n] + Bx[34 * 256 + n];
                #pragma unroll
                for (int k = 0; k < 32; ++k)
                    a += atv[k] * Bx[k * 256 + n];
                y0b[gt][b] = a;
            }
        }
        #pragma unroll
        for (int gt = 0; gt < 4; ++gt) {
            const int n = gt * 64 + l;
            Dsel[gt] = Bx[33 * 256 + n] - Bx[32 * 256 + n];
        }
    }

    // logit DIFF column frags (col 0 = W_amp[:,1]-W_amp[:,0]; others 0) — NOT scaled
    bf16x8 BLd0, BLd1;
    f32x4 CL0;                 // static C-input, bias folded
    {
        #pragma unroll
        for (int j = 0; j < 8; ++j) {
            int k = q * 8 + j;
            BLd0[j] = (n2 == 0) ? f2bf(W_amp[k * 2 + 1] - W_amp[k * 2]) : (short)0;
            BLd1[j] = (n2 == 0) ? f2bf(W_amp[(k + 32) * 2 + 1] - W_amp[(k + 32) * 2]) : (short)0;
        }
        float bd = (n2 == 0) ? (b_amp[1] - b_amp[0]) : 0.f;
        CL0[0] = bd; CL0[1] = bd; CL0[2] = bd; CL0[3] = bd;
    }
    const f32x4 z4 = {0.f, 0.f, 0.f, 0.f};

    // ---------- state init (cs = -2*L2E*c); lane l owns feature l ----------
    float cs0, cs1;
    {
        float g0 = g[bat0], g1 = g[bat0 + 1];
        cs0 = (-2.0f * L2E) * (g0 * W_gc[l] + b_gc[l]);
        cs1 = (-2.0f * L2E) * (g1 * W_gc[l] + b_gc[l]);
        Hl[w][0][l]      = f2bf(g0 * W_gh[l] + b_gh[l]);
        Hl[w][0][64 + l] = f2bf(g1 * W_gh[l] + b_gh[l]);
    }
    // no barrier: Hl[w] is wave-private; same-wave DS ops are in-order

    // ---------- main recurrence (barrier-free) ----------
    const int ra   = (l & 1) * 64 + q * 8;    // A-frag: batch = row&1 = l&1, feats q*8..+8
    const bool qb0 = (q & 1) != 0;
    const bool qb1 = (q & 2) != 0;
    const int bit0 = 2 * w, bit1 = 2 * w + 1;
    unsigned spt = 0;                          // sp_l[0]

    auto step = [&](int t, int rb, bool doLogit, bool doGate) {
        bf16x8 a0 = *(const bf16x8*)&Hl[w][rb][ra];        // K 0..31
        bf16x8 a1 = *(const bf16x8*)&Hl[w][rb][ra + 32];   // K 32..63
        unsigned spt_n = sp_l[t + 1];                      // prefetch next token byte
        const float f0 = (float)((spt >> bit0) & 1u);      // tokens s_pad[t] (wave-uniform)
        const float f1 = (float)((spt >> bit1) & 1u);

        float y[4][2];
        #pragma unroll
        for (int gt = 0; gt < 4; ++gt) {
            f32x4 c0 = __builtin_amdgcn_mfma_f32_16x16x32_bf16(a1, Bf[4 * gt + 0][1], z4, 0, 0, 0);
            c0 = __builtin_amdgcn_mfma_f32_16x16x32_bf16(a0, Bf[4 * gt + 0][0], c0, 0, 0, 0);
            f32x4 c1 = __builtin_amdgcn_mfma_f32_16x16x32_bf16(a1, Bf[4 * gt + 1][1], z4, 0, 0, 0);
            c1 = __builtin_amdgcn_mfma_f32_16x16x32_bf16(a0, Bf[4 * gt + 1][0], c1, 0, 0, 0);
            f32x4 c2 = __builtin_amdgcn_mfma_f32_16x16x32_bf16(a1, Bf[4 * gt + 2][1], z4, 0, 0, 0);
            c2 = __builtin_amdgcn_mfma_f32_16x16x32_bf16(a0, Bf[4 * gt + 2][0], c2, 0, 0, 0);
            f32x4 c3 = __builtin_amdgcn_mfma_f32_16x16x32_bf16(a1, Bf[4 * gt + 3][1], z4, 0, 0, 0);
            c3 = __builtin_amdgcn_mfma_f32_16x16x32_bf16(a0, Bf[4 * gt + 3][0], c3, 0, 0, 0);
            // lane's col n = gt*64 + l lives in tile gt*4+q, col n2, reg b (=batch)
            #pragma unroll
            for (int b = 0; b < 2; ++b) {
                float s01 = qb0 ? c1[b] : c0[b];
                float s23 = qb0 ? c3[b] : c2[b];
                y[gt][b] = (qb1 ? s23 : s01) + y0b[gt][b];
            }
        }

        if (doLogit) {
            f32x4 aL = __builtin_amdgcn_mfma_f32_16x16x32_bf16(a1, BLd1, CL0, 0, 0, 0);
            aL = __builtin_amdgcn_mfma_f32_16x16x32_bf16(a0, BLd0, aL, 0, 0, 0);
            if (l == 0) {                     // raw diffs for own 2 batches
                float2 d2; d2.x = aL[0]; d2.y = aL[1];
                *(float2*)&dLb[(t - 1) * 8 + 2 * w] = d2;
            }
        }

        if (doGate) {
            // token fold + dual independent activation chains (states: batch 0, 1)
            float yi0 = __builtin_fmaf(f0, Dsel[0], y[0][0]);
            float yi1 = __builtin_fmaf(f1, Dsel[0], y[0][1]);
            float yf0 = __builtin_fmaf(f0, Dsel[1], y[1][0]);
            float yf1 = __builtin_fmaf(f1, Dsel[1], y[1][1]);
            float yg0 = __builtin_fmaf(f0, Dsel[2], y[2][0]);
            float yg1 = __builtin_fmaf(f1, Dsel[2], y[2][1]);
            float yo0 = __builtin_fmaf(f0, Dsel[3], y[3][0]);
            float yo1 = __builtin_fmaf(f1, Dsel[3], y[3][1]);
            // y's are -L2E*z (i,f,o) and -2*L2E*z (g)
            float si0 = __builtin_amdgcn_rcpf(1.0f + __builtin_amdgcn_exp2f(yi0));
            float si1 = __builtin_amdgcn_rcpf(1.0f + __builtin_amdgcn_exp2f(yi1));
            float sf0 = __builtin_amdgcn_rcpf(1.0f + __builtin_amdgcn_exp2f(yf0));
            float sf1 = __builtin_amdgcn_rcpf(1.0f + __builtin_amdgcn_exp2f(yf1));
            float rg0 = __builtin_amdgcn_rcpf(1.0f + __builtin_amdgcn_exp2f(yg0));
            float rg1 = __builtin_amdgcn_rcpf(1.0f + __builtin_amdgcn_exp2f(yg1));
            float so0 = __builtin_amdgcn_rcpf(1.0f + __builtin_amdgcn_exp2f(yo0));
            float so1 = __builtin_amdgcn_rcpf(1.0f + __builtin_amdgcn_exp2f(yo1));
            float tgs0 = __builtin_fmaf(-4.0f * L2E, rg0, 2.0f * L2E);   // -2*L2E*tanh(zg)
            float tgs1 = __builtin_fmaf(-4.0f * L2E, rg1, 2.0f * L2E);
            cs0 = __builtin_fmaf(sf0, cs0, si0 * tgs0);
            cs1 = __builtin_fmaf(sf1, cs1, si1 * tgs1);
            float so20 = so0 + so0;               // off-chain (ready before r5)
            float so21 = so1 + so1;
            float r50 = __builtin_amdgcn_rcpf(1.0f + __builtin_amdgcn_exp2f(cs0));
            float r51 = __builtin_amdgcn_rcpf(1.0f + __builtin_amdgcn_exp2f(cs1));
            float h0 = __builtin_fmaf(so20, r50, -so0);   // so*(2*r5-1)
            float h1 = __builtin_fmaf(so21, r51, -so1);
            unsigned hv;
            asm("v_cvt_pk_bf16_f32 %0, %1, %2" : "=v"(hv) : "v"(h0), "v"(h1));
            Hl[w][rb ^ 1][l]      = (short)hv;
            Hl[w][rb ^ 1][64 + l] = (short)(hv >> 16);
        }
        spt = spt_n;
    };

    step(0, 0, false, true);
    for (int t = 1; t < 256; t += 2) {
        step(t, 1, true, true);
        step(t + 1, 0, true, true);
    }
    // covered t=1..256 (logit positions 0..255; t=256's gate output unused)

    __syncthreads();   // single barrier: make all waves' stashes visible

    // ---------- epilogue: deferred softplus (3 stages) ----------
    {
        // stage 1: thread tid handles stash row t=tid (8 batches); bias already folded
        unsigned bits = (unsigned)sp_l[tid + 1];
        f32x4 v0 = *(const f32x4*)&dLb[tid * 8];
        f32x4 v1 = *(const f32x4*)&dLb[tid * 8 + 4];
        f32x4 s0, s1;
        #pragma unroll
        for (int r = 0; r < 4; ++r) {
            float x0 = ((bits >> r) & 1u) ? -v0[r] : v0[r];    // l_other - l_token
            s0[r] = __builtin_amdgcn_logf(1.0f + __builtin_amdgcn_exp2f(L2E * x0));
            float x1 = ((bits >> (r + 4)) & 1u) ? -v1[r] : v1[r];
            s1[r] = __builtin_amdgcn_logf(1.0f + __builtin_amdgcn_exp2f(L2E * x1));
        }
        *(f32x4*)&dLb[tid * 8]     = s0;
        *(f32x4*)&dLb[tid * 8 + 4] = s1;
        __syncthreads();
        // stage 2: thread (b = tid>>5, j = tid&31) sums 8 rows
        {
            int b = tid >> 5, j = tid & 31;
            float sum = 0.f;
            #pragma unroll
            for (int k = 0; k < 8; ++k)
                sum += dLb[(j * 8 + k) * 8 + b];
            red2[b][j] = sum;
        }
        __syncthreads();
        // stage 3
        if (tid < 8) {
            float sum = 0.f;
            #pragma unroll
            for (int j2 = 0; j2 < 32; ++j2) sum += red2[tid][j2];
            out[wgb + tid] = -LN2 * sum;
        }
    }
}

extern "C" void kernel_launch(void* const* d_in, const int* in_sizes, int n_in,
                              void* d_out, int out_size, void* d_ws, size_t ws_size,
                              hipStream_t stream) {
    (void)in_sizes; (void)n_in; (void)out_size; (void)d_ws; (void)ws_size;
    const int*   s      = (const int*)d_in[0];
    const float* g      = (const float*)d_in[1];
    const float* W_emb  = (const float*)d_in[2];
    const float* b_emb  = (const float*)d_in[3];
    const float* W_g1   = (const float*)d_in[4];
    const float* b_g1   = (const float*)d_in[5];
    const float* W_g2   = (const float*)d_in[6];
    const float* b_g2   = (const float*)d_in[7];
    const float* W_gh   = (const float*)d_in[8];
    const float* b_gh   = (const float*)d_in[9];
    const float* W_gc   = (const float*)d_in[10];
    const float* b_gc   = (const float*)d_in[11];
    const float* Wi     = (const float*)d_in[12];
    const float* Wh     = (const float*)d_in[13];
    const float* b_lstm = (const float*)d_in[14];
    const float* W_amp  = (const float*)d_in[15];
    const float* b_amp  = (const float*)d_in[16];
    float* out = (float*)d_out;

    lstm_kernel<<<256, 256, 0, stream>>>(s, g, W_emb, b_emb, W_g1, b_g1, W_g2, b_g2,
                                         W_gh, b_gh, W_gc, b_gc, Wi, Wh, b_lstm,
                                         W_amp, b_amp, out);
}

// Round 13
// 308.688 us; speedup vs baseline: 1.0407x; 1.0407x over previous
//
#include <hip/hip_runtime.h>

// LSTM RNN: B=2048, L=256 (257 scan steps), F=64, H=32, K=2.
// R14: R13 (barrier-free, 2 batches/wave, 1 wave/SIMD) with the register
//  budget opened. R13 hit the 256-VGPR allocator ceiling (no min-waves hint)
//  and spilled 46.6MB/dispatch to scratch -> 256us was pure spill traffic.
//  Fix: __launch_bounds__(256, 1) (min 1 wave/EU -> up to 512 VGPRs; m08:
//  no-spill through ~450) + per-gate scalar extraction right after each
//  gate's 4 tiles (caps live accumulators at 4 f32x4 instead of 16).
//  Structure unchanged: 256 wgs x 4 waves; wave owns 2 batches END-TO-END;
//  32 gate MFMA + 2 logit MFMA per step; h-exchange intra-wave via per-wave
//  LDS (same-wave DS in-order -> zero __syncthreads in the 257-step loop);
//  raw logit stash, softplus in 3-stage epilogue.
//  Gate cols pre-scaled by -L2E (i,f,o) / -2*L2E (g); cs = -2*L2E*c.

typedef __attribute__((ext_vector_type(8))) short bf16x8;
typedef __attribute__((ext_vector_type(4))) float f32x4;

#define L2E 1.44269504088896340736f
#define LN2 0.69314718055994530942f

__device__ __forceinline__ short f2bf(float x) {
    unsigned u = __builtin_bit_cast(unsigned, x);
    unsigned r = (u + 0x7FFFu + ((u >> 16) & 1u)) >> 16;
    return (short)r;
}

__global__ __launch_bounds__(256, 1) void lstm_kernel(
    const int* __restrict__ s, const float* __restrict__ g,
    const float* __restrict__ W_emb, const float* __restrict__ b_emb,
    const float* __restrict__ W_g1, const float* __restrict__ b_g1,
    const float* __restrict__ W_g2, const float* __restrict__ b_g2,
    const float* __restrict__ W_gh, const float* __restrict__ b_gh,
    const float* __restrict__ W_gc, const float* __restrict__ b_gc,
    const float* __restrict__ Wi, const float* __restrict__ Wh,
    const float* __restrict__ b_lstm, const float* __restrict__ W_amp,
    const float* __restrict__ b_amp, float* __restrict__ out)
{
    __shared__ float Bx[35 * 256];              // 0-31: W_g2@Wi; 32-33: W_emb@Wi; 34: const (pre-scaled)
    __shared__ unsigned char sp_l[260];         // packed tokens: bit b of sp_l[t] = s_pad[b][t], 8 batches
    __shared__ __align__(16) short Hl[4][2][128]; // per-wave h dbuf: [batch(2)*64 + f]
    __shared__ __align__(16) float dLb[256 * 8];// raw logit diffs (bias folded): [t(256)][b(8)]
    __shared__ float red2[8][32];               // epilogue partials

    const int tid = threadIdx.x;
    const int w   = tid >> 6;     // wave 0..3; owns batches 2w, 2w+1
    const int l   = tid & 63;     // lane; owns feature f = l of both batches
    const int n2  = l & 15;       // MFMA col
    const int q   = l >> 4;       // MFMA k-quad
    const int wgb = blockIdx.x * 8;
    const int bat0 = wgb + 2 * w;

    // ---------- Setup: folded B rows into LDS, pre-scaled by activation constants ----------
    {
        const int n = tid;
        // cols [0,64)=i, [64,128)=f: -L2E; [128,192)=g: -2*L2E; [192,256)=o: -L2E
        const float sc = (n >= 128 && n < 192) ? (-2.0f * L2E) : (-L2E);
        float acc[35];
        #pragma unroll
        for (int i = 0; i < 35; ++i) acc[i] = 0.f;
        for (int f = 0; f < 64; ++f) {
            float wi = Wi[f * 256 + n] * sc;
            #pragma unroll
            for (int k = 0; k < 32; ++k) acc[k] += W_g2[k * 64 + f] * wi;  // uniform
            acc[32] += W_emb[f] * wi;
            acc[33] += W_emb[64 + f] * wi;
            acc[34] += (b_emb[f] + b_g2[f]) * wi;
        }
        acc[34] += b_lstm[n] * sc;
        #pragma unroll
        for (int i = 0; i < 35; ++i) Bx[i * 256 + n] = acc[i];
        // token staging: sp_l[t+1] bits = s[:, t] for 8 batch rows
        unsigned v = 0;
        #pragma unroll
        for (int b = 0; b < 8; ++b)
            v |= (unsigned)(s[(wgb + b) * 256 + n] & 1) << b;
        sp_l[n + 1] = (unsigned char)v;
        if (n == 0) sp_l[0] = 0;
        if (n < 3) sp_l[257 + n] = 0;
    }
    __syncthreads();

    // ---------- static fragments: full Wh (16 col-tiles x K-chain 2), pre-scaled ----------
    bf16x8 Bf[16][2];   // 128 VGPRs
    #pragma unroll
    for (int m = 0; m < 16; ++m) {
        const int n = m * 16 + n2;
        const float scg = (m >= 8 && m < 12) ? (-2.0f * L2E) : (-L2E);
        #pragma unroll
        for (int kf = 0; kf < 2; ++kf)
            #pragma unroll
            for (int j = 0; j < 8; ++j)
                Bf[m][kf][j] = f2bf(Wh[(kf * 32 + q * 8 + j) * 256 + n] * scg);
    }

    // per-lane gate base consts at col n = gt*64 + l, for both batches
    float y0b[4][2], Dsel[4];
    {
        #pragma unroll
        for (int b = 0; b < 2; ++b) {
            const float gb = g[bat0 + b];
            float atv[32];
            #pragma unroll
            for (int k = 0; k < 32; ++k)
                atv[k] = tanhf(gb * W_g1[k] + b_g1[k]);
            #pragma unroll
            for (int gt = 0; gt < 4; ++gt) {
                const int n = gt * 64 + l;
                float a = Bx[32 * 256 + n] + Bx[34 * 256 + n];
                #pragma unroll
                for (int k = 0; k < 32; ++k)
                    a += atv[k] * Bx[k * 256 + n];
                y0b[gt][b] = a;
            }
        }
        #pragma unroll
        for (int gt = 0; gt < 4; ++gt) {
            const int n = gt * 64 + l;
            Dsel[gt] = Bx[33 * 256 + n] - Bx[32 * 256 + n];
        }
    }

    // logit DIFF column frags (col 0 = W_amp[:,1]-W_amp[:,0]; others 0) — NOT scaled
    bf16x8 BLd0, BLd1;
    f32x4 CL0;                 // static C-input, bias folded
    {
        #pragma unroll
        for (int j = 0; j < 8; ++j) {
            int k = q * 8 + j;
            BLd0[j] = (n2 == 0) ? f2bf(W_amp[k * 2 + 1] - W_amp[k * 2]) : (short)0;
            BLd1[j] = (n2 == 0) ? f2bf(W_amp[(k + 32) * 2 + 1] - W_amp[(k + 32) * 2]) : (short)0;
        }
        float bd = (n2 == 0) ? (b_amp[1] - b_amp[0]) : 0.f;
        CL0[0] = bd; CL0[1] = bd; CL0[2] = bd; CL0[3] = bd;
    }
    const f32x4 z4 = {0.f, 0.f, 0.f, 0.f};

    // ---------- state init (cs = -2*L2E*c); lane l owns feature l ----------
    float cs0, cs1;
    {
        float g0 = g[bat0], g1 = g[bat0 + 1];
        cs0 = (-2.0f * L2E) * (g0 * W_gc[l] + b_gc[l]);
        cs1 = (-2.0f * L2E) * (g1 * W_gc[l] + b_gc[l]);
        Hl[w][0][l]      = f2bf(g0 * W_gh[l] + b_gh[l]);
        Hl[w][0][64 + l] = f2bf(g1 * W_gh[l] + b_gh[l]);
    }
    // no barrier: Hl[w] is wave-private; same-wave DS ops are in-order

    // ---------- main recurrence (barrier-free) ----------
    const int ra   = (l & 1) * 64 + q * 8;    // A-frag: batch = row&1 = l&1, feats q*8..+8
    const bool qb0 = (q & 1) != 0;
    const bool qb1 = (q & 2) != 0;
    const int bit0 = 2 * w, bit1 = 2 * w + 1;
    unsigned spt = 0;                          // sp_l[0]

    auto step = [&](int t, int rb, bool doLogit, bool doGate) {
        bf16x8 a0 = *(const bf16x8*)&Hl[w][rb][ra];        // K 0..31
        bf16x8 a1 = *(const bf16x8*)&Hl[w][rb][ra + 32];   // K 32..63
        unsigned spt_n = sp_l[t + 1];                      // prefetch next token byte
        const float f0 = (float)((spt >> bit0) & 1u);      // tokens s_pad[t] (wave-uniform)
        const float f1 = (float)((spt >> bit1) & 1u);

        // per-gate: 4 tiles live at a time, scalars extracted immediately
        float y[4][2];
        #pragma unroll
        for (int gt = 0; gt < 4; ++gt) {
            f32x4 c0 = __builtin_amdgcn_mfma_f32_16x16x32_bf16(a1, Bf[4 * gt + 0][1], z4, 0, 0, 0);
            f32x4 c1 = __builtin_amdgcn_mfma_f32_16x16x32_bf16(a1, Bf[4 * gt + 1][1], z4, 0, 0, 0);
            f32x4 c2 = __builtin_amdgcn_mfma_f32_16x16x32_bf16(a1, Bf[4 * gt + 2][1], z4, 0, 0, 0);
            f32x4 c3 = __builtin_amdgcn_mfma_f32_16x16x32_bf16(a1, Bf[4 * gt + 3][1], z4, 0, 0, 0);
            c0 = __builtin_amdgcn_mfma_f32_16x16x32_bf16(a0, Bf[4 * gt + 0][0], c0, 0, 0, 0);
            c1 = __builtin_amdgcn_mfma_f32_16x16x32_bf16(a0, Bf[4 * gt + 1][0], c1, 0, 0, 0);
            c2 = __builtin_amdgcn_mfma_f32_16x16x32_bf16(a0, Bf[4 * gt + 2][0], c2, 0, 0, 0);
            c3 = __builtin_amdgcn_mfma_f32_16x16x32_bf16(a0, Bf[4 * gt + 3][0], c3, 0, 0, 0);
            // lane's col n = gt*64 + l lives in tile gt*4+q, col n2, reg b (=batch)
            #pragma unroll
            for (int b = 0; b < 2; ++b) {
                float s01 = qb0 ? c1[b] : c0[b];
                float s23 = qb0 ? c3[b] : c2[b];
                y[gt][b] = (qb1 ? s23 : s01) + y0b[gt][b];
            }
        }

        if (doLogit) {
            f32x4 aL = __builtin_amdgcn_mfma_f32_16x16x32_bf16(a1, BLd1, CL0, 0, 0, 0);
            aL = __builtin_amdgcn_mfma_f32_16x16x32_bf16(a0, BLd0, aL, 0, 0, 0);
            if (l == 0) {                     // raw diffs for own 2 batches
                float2 d2; d2.x = aL[0]; d2.y = aL[1];
                *(float2*)&dLb[(t - 1) * 8 + 2 * w] = d2;
            }
        }

        if (doGate) {
            // token fold + dual independent activation chains (states: batch 0, 1)
            float yi0 = __builtin_fmaf(f0, Dsel[0], y[0][0]);
            float yi1 = __builtin_fmaf(f1, Dsel[0], y[0][1]);
            float yf0 = __builtin_fmaf(f0, Dsel[1], y[1][0]);
            float yf1 = __builtin_fmaf(f1, Dsel[1], y[1][1]);
            float yg0 = __builtin_fmaf(f0, Dsel[2], y[2][0]);
            float yg1 = __builtin_fmaf(f1, Dsel[2], y[2][1]);
            float yo0 = __builtin_fmaf(f0, Dsel[3], y[3][0]);
            float yo1 = __builtin_fmaf(f1, Dsel[3], y[3][1]);
            // y's are -L2E*z (i,f,o) and -2*L2E*z (g)
            float si0 = __builtin_amdgcn_rcpf(1.0f + __builtin_amdgcn_exp2f(yi0));
            float si1 = __builtin_amdgcn_rcpf(1.0f + __builtin_amdgcn_exp2f(yi1));
            float sf0 = __builtin_amdgcn_rcpf(1.0f + __builtin_amdgcn_exp2f(yf0));
            float sf1 = __builtin_amdgcn_rcpf(1.0f + __builtin_amdgcn_exp2f(yf1));
            float rg0 = __builtin_amdgcn_rcpf(1.0f + __builtin_amdgcn_exp2f(yg0));
            float rg1 = __builtin_amdgcn_rcpf(1.0f + __builtin_amdgcn_exp2f(yg1));
            float so0 = __builtin_amdgcn_rcpf(1.0f + __builtin_amdgcn_exp2f(yo0));
            float so1 = __builtin_amdgcn_rcpf(1.0f + __builtin_amdgcn_exp2f(yo1));
            float tgs0 = __builtin_fmaf(-4.0f * L2E, rg0, 2.0f * L2E);   // -2*L2E*tanh(zg)
            float tgs1 = __builtin_fmaf(-4.0f * L2E, rg1, 2.0f * L2E);
            cs0 = __builtin_fmaf(sf0, cs0, si0 * tgs0);
            cs1 = __builtin_fmaf(sf1, cs1, si1 * tgs1);
            float so20 = so0 + so0;               // off-chain (ready before r5)
            float so21 = so1 + so1;
            float r50 = __builtin_amdgcn_rcpf(1.0f + __builtin_amdgcn_exp2f(cs0));
            float r51 = __builtin_amdgcn_rcpf(1.0f + __builtin_amdgcn_exp2f(cs1));
            float h0 = __builtin_fmaf(so20, r50, -so0);   // so*(2*r5-1)
            float h1 = __builtin_fmaf(so21, r51, -so1);
            unsigned hv;
            asm("v_cvt_pk_bf16_f32 %0, %1, %2" : "=v"(hv) : "v"(h0), "v"(h1));
            Hl[w][rb ^ 1][l]      = (short)hv;
            Hl[w][rb ^ 1][64 + l] = (short)(hv >> 16);
        }
        spt = spt_n;
    };

    step(0, 0, false, true);
    for (int t = 1; t < 256; t += 2) {
        step(t, 1, true, true);
        step(t + 1, 0, true, true);
    }
    // covered t=1..256 (logit positions 0..255; t=256's gate output unused)

    __syncthreads();   // single barrier: make all waves' stashes visible

    // ---------- epilogue: deferred softplus (3 stages) ----------
    {
        // stage 1: thread tid handles stash row t=tid (8 batches); bias already folded
        unsigned bits = (unsigned)sp_l[tid + 1];
        f32x4 v0 = *(const f32x4*)&dLb[tid * 8];
        f32x4 v1 = *(const f32x4*)&dLb[tid * 8 + 4];
        f32x4 s0, s1;
        #pragma unroll
        for (int r = 0; r < 4; ++r) {
            float x0 = ((bits >> r) & 1u) ? -v0[r] : v0[r];    // l_other - l_token
            s0[r] = __builtin_amdgcn_logf(1.0f + __builtin_amdgcn_exp2f(L2E * x0));
            float x1 = ((bits >> (r + 4)) & 1u) ? -v1[r] : v1[r];
            s1[r] = __builtin_amdgcn_logf(1.0f + __builtin_amdgcn_exp2f(L2E * x1));
        }
        *(f32x4*)&dLb[tid * 8]     = s0;
        *(f32x4*)&dLb[tid * 8 + 4] = s1;
        __syncthreads();
        // stage 2: thread (b = tid>>5, j = tid&31) sums 8 rows
        {
            int b = tid >> 5, j = tid & 31;
            float sum = 0.f;
            #pragma unroll
            for (int k = 0; k < 8; ++k)
                sum += dLb[(j * 8 + k) * 8 + b];
            red2[b][j] = sum;
        }
        __syncthreads();
        // stage 3
        if (tid < 8) {
            float sum = 0.f;
            #pragma unroll
            for (int j2 = 0; j2 < 32; ++j2) sum += red2[tid][j2];
            out[wgb + tid] = -LN2 * sum;
        }
    }
}

extern "C" void kernel_launch(void* const* d_in, const int* in_sizes, int n_in,
                              void* d_out, int out_size, void* d_ws, size_t ws_size,
                              hipStream_t stream) {
    (void)in_sizes; (void)n_in; (void)out_size; (void)d_ws; (void)ws_size;
    const int*   s      = (const int*)d_in[0];
    const float* g      = (const float*)d_in[1];
    const float* W_emb  = (const float*)d_in[2];
    const float* b_emb  = (const float*)d_in[3];
    const float* W_g1   = (const float*)d_in[4];
    const float* b_g1   = (const float*)d_in[5];
    const float* W_g2   = (const float*)d_in[6];
    const float* b_g2   = (const float*)d_in[7];
    const float* W_gh   = (const float*)d_in[8];
    const float* b_gh   = (const float*)d_in[9];
    const float* W_gc   = (const float*)d_in[10];
    const float* b_gc   = (const float*)d_in[11];
    const float* Wi     = (const float*)d_in[12];
    const float* Wh     = (const float*)d_in[13];
    const float* b_lstm = (const float*)d_in[14];
    const float* W_amp  = (const float*)d_in[15];
    const float* b_amp  = (const float*)d_in[16];
    float* out = (float*)d_out;

    lstm_kernel<<<256, 256, 0, stream>>>(s, g, W_emb, b_emb, W_g1, b_g1, W_g2, b_g2,
                                         W_gh, b_gh, W_gc, b_gc, Wi, Wh, b_lstm,
                                         W_amp, b_amp, out);
}

// Round 16
// 234.693 us; speedup vs baseline: 1.3688x; 1.3153x over previous
//
#include <hip/hip_runtime.h>

// LSTM RNN: B=2048, L=256 (257 scan steps), F=64, H=32, K=2.
// R15 (resubmit #3; two broker-capacity timeouts, kernel has never run):
//  2-WAVE workgroups — halve the barrier rendezvous width vs R10.
//  512 wgs x 128 thr (2 waves); wg owns 4 batches. A-rows dup x4 -> batch =
//  row>>2 = q (lane-quad); ALL C-rows of a lane are its quad's batch.
//  Wave w computes 128 gate cols = 32 feats x 4 gates: 8 tiles x K-chain 2
//  = 16 MFMA/step (Bf = 64 VGPRs; total ~190 -> fits the 256 arch-VGPR cap,
//  no spill — the full-Wh family R6/R13/R14 could not).
//  Gate select vanishes: lane's gate gt, feat-half h value = acc[gt*2+h][0].
//  Token fold: single (spt>>q)&1 per lane. rr logit rotates over 2 waves
//  (slot = t&1), raw stash pre-barrier (R10's proven order), softplus in
//  3-stage epilogue. Gate cols pre-scaled -L2E / -2*L2E; cs = -2*L2E*c.
// h exchange: 4x80-short double buffer (160B batch stride, 16B aligned).

typedef __attribute__((ext_vector_type(8))) short bf16x8;
typedef __attribute__((ext_vector_type(4))) float f32x4;

#define L2E 1.44269504088896340736f
#define LN2 0.69314718055994530942f

__device__ __forceinline__ short f2bf(float x) {
    unsigned u = __builtin_bit_cast(unsigned, x);
    unsigned r = (u + 0x7FFFu + ((u >> 16) & 1u)) >> 16;
    return (short)r;
}

__global__ __launch_bounds__(128) void lstm_kernel(
    const int* __restrict__ s, const float* __restrict__ g,
    const float* __restrict__ W_emb, const float* __restrict__ b_emb,
    const float* __restrict__ W_g1, const float* __restrict__ b_g1,
    const float* __restrict__ W_g2, const float* __restrict__ b_g2,
    const float* __restrict__ W_gh, const float* __restrict__ b_gh,
    const float* __restrict__ W_gc, const float* __restrict__ b_gc,
    const float* __restrict__ Wi, const float* __restrict__ Wh,
    const float* __restrict__ b_lstm, const float* __restrict__ W_amp,
    const float* __restrict__ b_amp, float* __restrict__ out)
{
    __shared__ float Bx[35 * 256];              // 0-31: W_g2@Wi; 32-33: W_emb@Wi; 34: const (pre-scaled)
    __shared__ unsigned char sp_l[260];         // packed tokens: bit b of sp_l[t] = s_pad[b][t], 4 batches
    __shared__ __align__(16) short Hb[2][320];  // h dbuf: [b(4) * 80 + f(64)] bf16
    __shared__ __align__(16) float dLb[256 * 4];// raw logit diffs (bias folded): [t(256)][b(4)]
    __shared__ float red2[4][32];               // epilogue partials

    const int tid = threadIdx.x;
    const int w   = tid >> 6;     // wave 0..1
    const int l   = tid & 63;     // lane
    const int n2  = l & 15;       // MFMA col
    const int q   = l >> 4;       // MFMA k-quad == owned batch (dup x4)
    const int wgb = blockIdx.x * 4;

    // ---------- Setup: folded B rows into LDS, pre-scaled (2 cols per thread) ----------
    for (int n = tid; n < 256; n += 128) {
        // cols [0,64)=i, [64,128)=f: -L2E; [128,192)=g: -2*L2E; [192,256)=o: -L2E
        const float sc = (n >= 128 && n < 192) ? (-2.0f * L2E) : (-L2E);
        float acc[35];
        #pragma unroll
        for (int i = 0; i < 35; ++i) acc[i] = 0.f;
        for (int f = 0; f < 64; ++f) {
            float wi = Wi[f * 256 + n] * sc;
            #pragma unroll
            for (int k = 0; k < 32; ++k) acc[k] += W_g2[k * 64 + f] * wi;  // uniform
            acc[32] += W_emb[f] * wi;
            acc[33] += W_emb[64 + f] * wi;
            acc[34] += (b_emb[f] + b_g2[f]) * wi;
        }
        acc[34] += b_lstm[n] * sc;
        #pragma unroll
        for (int i = 0; i < 35; ++i) Bx[i * 256 + n] = acc[i];
        // token staging: sp_l[t+1] bits = s[:, t] for 4 batch rows
        unsigned v = 0;
        #pragma unroll
        for (int b = 0; b < 4; ++b)
            v |= (unsigned)(s[(wgb + b) * 256 + n] & 1) << b;
        sp_l[n + 1] = (unsigned char)v;
    }
    if (tid == 0) sp_l[0] = 0;
    __syncthreads();

    // ---------- static fragments: wave's 8 tiles (cols gt*64 + w*32 + h*16 + n2) ----------
    bf16x8 Bf[8][2];          // 64 VGPRs
    float  Dsel[8];
    f32x4  C0b[8];            // STATIC C-init (broadcast per lane; batch = q)
    {
        bf16x8 B2f[8];
        float c0add[8];
        #pragma unroll
        for (int m = 0; m < 8; ++m) {
            const int gt = m >> 1, h = m & 1;
            const int n  = gt * 64 + w * 32 + h * 16 + n2;
            const float scg = (gt == 2) ? (-2.0f * L2E) : (-L2E);
            #pragma unroll
            for (int kf = 0; kf < 2; ++kf)
                #pragma unroll
                for (int j = 0; j < 8; ++j)
                    Bf[m][kf][j] = f2bf(Wh[(kf * 32 + q * 8 + j) * 256 + n] * scg);
            #pragma unroll
            for (int j = 0; j < 8; ++j)
                B2f[m][j] = f2bf(Bx[(q * 8 + j) * 256 + n]);
            c0add[m] = Bx[32 * 256 + n] + Bx[34 * 256 + n];
            Dsel[m]  = Bx[33 * 256 + n] - Bx[32 * 256 + n];
        }
        // Atv static A-frag; dup pattern: A row r -> batch r>>2
        const float g_a = g[wgb + ((l & 15) >> 2)];
        bf16x8 Atv;
        #pragma unroll
        for (int j = 0; j < 8; ++j) {
            int k = q * 8 + j;
            Atv[j] = f2bf(tanhf(g_a * W_g1[k] + b_g1[k]));
        }
        const f32x4 zero4 = {0.f, 0.f, 0.f, 0.f};
        #pragma unroll
        for (int m = 0; m < 8; ++m) {
            f32x4 c = __builtin_amdgcn_mfma_f32_16x16x32_bf16(Atv, B2f[m], zero4, 0, 0, 0);
            float cv = c[0] + c0add[m];    // row q*4 -> batch q; all rows of lane = batch q
            C0b[m][0] = cv; C0b[m][1] = cv; C0b[m][2] = cv; C0b[m][3] = cv;
        }
    }
    // logit DIFF column frags (col 0 = W_amp[:,1]-W_amp[:,0]; others 0) — NOT scaled
    bf16x8 BLd0, BLd1;
    f32x4 CL0;                 // static C-input, bias folded
    {
        #pragma unroll
        for (int j = 0; j < 8; ++j) {
            int k = q * 8 + j;
            BLd0[j] = (n2 == 0) ? f2bf(W_amp[k * 2 + 1] - W_amp[k * 2]) : (short)0;
            BLd1[j] = (n2 == 0) ? f2bf(W_amp[(k + 32) * 2 + 1] - W_amp[(k + 32) * 2]) : (short)0;
        }
        float bd = (n2 == 0) ? (b_amp[1] - b_amp[0]) : 0.f;
        CL0[0] = bd; CL0[1] = bd; CL0[2] = bd; CL0[3] = bd;
    }

    // ---------- state init (cs = -2*L2E*c): thread owns (batch q, feats fA, fB) ----------
    const int fA = w * 32 + n2, fB = fA + 16;
    const int haddrA = q * 80 + fA;
    const int haddrB = q * 80 + fB;
    float csA, csB;
    {
        float gq = g[wgb + q];
        csA = (-2.0f * L2E) * (gq * W_gc[fA] + b_gc[fA]);
        csB = (-2.0f * L2E) * (gq * W_gc[fB] + b_gc[fB]);
        Hb[0][haddrA] = f2bf(gq * W_gh[fA] + b_gh[fA]);
        Hb[0][haddrB] = f2bf(gq * W_gh[fB] + b_gh[fB]);
    }
    __syncthreads();

    // ---------- main recurrence ----------
    const int ra = ((l & 15) >> 2) * 80 + q * 8;   // A-frag: batch (l&15)>>2, feats q*8..+8
    unsigned spt = 0;                              // sp_l[0]

    auto step = [&](int t, int rb, int slot, bool doGate) {
        bf16x8 a0 = *(const bf16x8*)&Hb[rb][ra];
        bf16x8 a1 = *(const bf16x8*)&Hb[rb][ra + 32];
        unsigned spt_n = sp_l[t + 1];             // prefetch next token byte
        const float fq = (float)((spt >> q) & 1u);    // this lane's batch token s_pad[t]

        f32x4 acc[8];
        #pragma unroll
        for (int m = 0; m < 8; ++m) {
            f32x4 a = __builtin_amdgcn_mfma_f32_16x16x32_bf16(a1, Bf[m][1], C0b[m], 0, 0, 0);
            acc[m] = __builtin_amdgcn_mfma_f32_16x16x32_bf16(a0, Bf[m][0], a, 0, 0, 0);
        }

        const bool rr = (w == slot) && (t >= 1);  // slot-static round-robin over 2 waves
        if (rr) {
            f32x4 aL = __builtin_amdgcn_mfma_f32_16x16x32_bf16(a1, BLd1, CL0, 0, 0, 0);
            aL = __builtin_amdgcn_mfma_f32_16x16x32_bf16(a0, BLd0, aL, 0, 0, 0);
            if (n2 == 0)                          // lanes q*16: batch q raw diff
                dLb[(t - 1) * 4 + q] = aL[0];
        }

        if (doGate) {
            // no gate select: value for gate gt, feat-half h = acc[gt*2+h][0]
            float yiA = __builtin_fmaf(fq, Dsel[0], acc[0][0]);
            float yiB = __builtin_fmaf(fq, Dsel[1], acc[1][0]);
            float yfA = __builtin_fmaf(fq, Dsel[2], acc[2][0]);
            float yfB = __builtin_fmaf(fq, Dsel[3], acc[3][0]);
            float ygA = __builtin_fmaf(fq, Dsel[4], acc[4][0]);
            float ygB = __builtin_fmaf(fq, Dsel[5], acc[5][0]);
            float yoA = __builtin_fmaf(fq, Dsel[6], acc[6][0]);
            float yoB = __builtin_fmaf(fq, Dsel[7], acc[7][0]);
            // y's are -L2E*z (i,f,o) and -2*L2E*z (g)
            float siA = __builtin_amdgcn_rcpf(1.0f + __builtin_amdgcn_exp2f(yiA));
            float siB = __builtin_amdgcn_rcpf(1.0f + __builtin_amdgcn_exp2f(yiB));
            float sfA = __builtin_amdgcn_rcpf(1.0f + __builtin_amdgcn_exp2f(yfA));
            float sfB = __builtin_amdgcn_rcpf(1.0f + __builtin_amdgcn_exp2f(yfB));
            float rgA = __builtin_amdgcn_rcpf(1.0f + __builtin_amdgcn_exp2f(ygA));
            float rgB = __builtin_amdgcn_rcpf(1.0f + __builtin_amdgcn_exp2f(ygB));
            float soA = __builtin_amdgcn_rcpf(1.0f + __builtin_amdgcn_exp2f(yoA));
            float soB = __builtin_amdgcn_rcpf(1.0f + __builtin_amdgcn_exp2f(yoB));
            float tgsA = __builtin_fmaf(-4.0f * L2E, rgA, 2.0f * L2E);   // -2*L2E*tanh(zg)
            float tgsB = __builtin_fmaf(-4.0f * L2E, rgB, 2.0f * L2E);
            csA = __builtin_fmaf(sfA, csA, siA * tgsA);
            csB = __builtin_fmaf(sfB, csB, siB * tgsB);
            float so2A = soA + soA;               // off-chain (ready before r5)
            float so2B = soB + soB;
            float r5A = __builtin_amdgcn_rcpf(1.0f + __builtin_amdgcn_exp2f(csA));
            float r5B = __builtin_amdgcn_rcpf(1.0f + __builtin_amdgcn_exp2f(csB));
            float hA  = __builtin_fmaf(so2A, r5A, -soA);   // so*(2*r5-1)
            float hB  = __builtin_fmaf(so2B, r5B, -soB);
            unsigned hv;
            asm("v_cvt_pk_bf16_f32 %0, %1, %2" : "=v"(hv) : "v"(hA), "v"(hB));
            Hb[1 - rb][haddrA] = (short)hv;
            Hb[1 - rb][haddrB] = (short)(hv >> 16);
        }
        spt = spt_n;
        __syncthreads();
    };

    step(0, 0, 0, true);
    for (int t0 = 1; t0 < 256; t0 += 2) {
        step(t0, 1, 1, true);       // t odd:  rb=1, slot=1
        step(t0 + 1, 0, 0, true);   // t even: rb=0, slot=0
    }
    step(256, 0, 0, false);   // final logit step, no gate phase

    // ---------- epilogue: deferred softplus (3 stages) ----------
    {
        // stage 1: 2 stash rows per thread (bias already folded)
        for (int u = tid; u < 256; u += 128) {
            unsigned bits = (unsigned)sp_l[u + 1];
            f32x4 v = *(const f32x4*)&dLb[u * 4];
            f32x4 so;
            #pragma unroll
            for (int r = 0; r < 4; ++r) {
                float x = ((bits >> r) & 1u) ? -v[r] : v[r];   // l_other - l_token
                so[r] = __builtin_amdgcn_logf(1.0f + __builtin_amdgcn_exp2f(L2E * x));
            }
            *(f32x4*)&dLb[u * 4] = so;
        }
        __syncthreads();
        // stage 2: thread (b = tid>>5, j = tid&31) sums 8 rows
        {
            int b = tid >> 5, j = tid & 31;
            float sum = 0.f;
            #pragma unroll
            for (int k = 0; k < 8; ++k)
                sum += dLb[(j * 8 + k) * 4 + b];
            red2[b][j] = sum;
        }
        __syncthreads();
        // stage 3
        if (tid < 4) {
            float sum = 0.f;
            #pragma unroll
            for (int j2 = 0; j2 < 32; ++j2) sum += red2[tid][j2];
            out[wgb + tid] = -LN2 * sum;
        }
    }
}

extern "C" void kernel_launch(void* const* d_in, const int* in_sizes, int n_in,
                              void* d_out, int out_size, void* d_ws, size_t ws_size,
                              hipStream_t stream) {
    (void)in_sizes; (void)n_in; (void)out_size; (void)d_ws; (void)ws_size;
    const int*   s      = (const int*)d_in[0];
    const float* g      = (const float*)d_in[1];
    const float* W_emb  = (const float*)d_in[2];
    const float* b_emb  = (const float*)d_in[3];
    const float* W_g1   = (const float*)d_in[4];
    const float* b_g1   = (const float*)d_in[5];
    const float* W_g2   = (const float*)d_in[6];
    const float* b_g2   = (const float*)d_in[7];
    const float* W_gh   = (const float*)d_in[8];
    const float* b_gh   = (const float*)d_in[9];
    const float* W_gc   = (const float*)d_in[10];
    const float* b_gc   = (const float*)d_in[11];
    const float* Wi     = (const float*)d_in[12];
    const float* Wh     = (const float*)d_in[13];
    const float* b_lstm = (const float*)d_in[14];
    const float* W_amp  = (const float*)d_in[15];
    const float* b_amp  = (const float*)d_in[16];
    float* out = (float*)d_out;

    lstm_kernel<<<512, 128, 0, stream>>>(s, g, W_emb, b_emb, W_g1, b_g1, W_g2, b_g2,
                                         W_gh, b_gh, W_gc, b_gc, Wi, Wh, b_lstm,
                                         W_amp, b_amp, out);
}